// Round 7
// baseline (106.533 us; speedup 1.0000x reference)
//
#include <hip/hip_runtime.h>
#include <hip/hip_bf16.h>

typedef __attribute__((ext_vector_type(8))) short short8;
typedef __attribute__((ext_vector_type(4))) float f32x4;
typedef __attribute__((address_space(1))) const void gvoid_t;
typedef __attribute__((address_space(3))) void lvoid_t;

#define NB 4096   // B
#define DD 256    // D
#define TWOB 8192
#define NMACRO 1056u   // packed 128x256 upper-triangle tiles
#define GSUM_BLOCKS 16
#define NPART 544u     // 16 gsum + 528 two-tile macro blocks (8 x 68)

__device__ __forceinline__ unsigned short f2bf(float f) {
  unsigned int u = __float_as_uint(f);
  u += 0x7fffu + ((u >> 16) & 1u);
  return (unsigned short)(u >> 16);
}
__device__ __forceinline__ float bf2f(unsigned short s) {
  return __uint_as_float(((unsigned int)s) << 16);
}

// ws layout (bytes):
//   [0, 32768)          den[8192] f32 (zeroed by norm blocks 0..31)
//   [32768, 32772)      done counter (zeroed by norm block 32)
//   [65536, 4259840)    znb 8192x256 bf16
//   [4259840, 4276224)  vsum_part[16][4][256] f32
//   [4276224, 4276480)  cnt_part[16][4] int
//   [4276480, 4280576)  ppos[1024] f32
//
// R24 (on R22 base; R23's 256^2/1-block-CU reverted): (1) persistent
// 2-tile macro blocks -- 16-step unified counted-vmcnt pipeline (3 bufs,
// dist 2) so tile1's stages fly during tile0's epilogue; epilogue uses
// dedicated Escr scratch + raw lgkmcnt(0)+s_barrier (NOT __syncthreads:
// its vmcnt(0) would drain the cross-tile prefetch). (2) tail fused via
// done-counter, lean protocol: producers __syncthreads (drains own
// atomics) + bump; only 16 gsum blocks __threadfence (flush plain vsum
// stores); last block agent-scope loads. ONE fence vs R18's 1072.
// (3) side effect: den+tail > fill cutoff -> PMC-visible next round.

// ---------------- kernel A: zero den+done; normalize -> znb; ppos ---------
__global__ __launch_bounds__(256) void norm_kernel(const float* __restrict__ zi,
                                                   const float* __restrict__ zj,
                                                   float* __restrict__ wsf,
                                                   float* __restrict__ ppos,
                                                   unsigned short* __restrict__ znb) {
  __shared__ float sred[4];
  if (blockIdx.x < 32) wsf[blockIdx.x * 256 + threadIdx.x] = 0.f;
  if (blockIdx.x == 32 && threadIdx.x == 0) ((int*)(wsf + 8192))[0] = 0;
  const int lane = threadIdx.x & 63, wave = threadIdx.x >> 6;
  const int i = blockIdx.x * 4 + wave;

  float4 a = ((const float4*)(zi + (size_t)i * DD))[lane];
  float4 b = ((const float4*)(zj + (size_t)i * DD))[lane];
  float sa = a.x * a.x + a.y * a.y + a.z * a.z + a.w * a.w;
  float sb = b.x * b.x + b.y * b.y + b.z * b.z + b.w * b.w;
  float sab = a.x * b.x + a.y * b.y + a.z * b.z + a.w * b.w;
#pragma unroll
  for (int m = 32; m >= 1; m >>= 1) {
    sa += __shfl_xor(sa, m);
    sb += __shfl_xor(sb, m);
    sab += __shfl_xor(sab, m);
  }
  float ra = 1.0f / fmaxf(sqrtf(sa), 1e-8f);
  float rb = 1.0f / fmaxf(sqrtf(sb), 1e-8f);
  ushort4 oa, ob;
  oa.x = f2bf(a.x * ra); oa.y = f2bf(a.y * ra); oa.z = f2bf(a.z * ra); oa.w = f2bf(a.w * ra);
  ob.x = f2bf(b.x * rb); ob.y = f2bf(b.y * rb); ob.z = f2bf(b.z * rb); ob.w = f2bf(b.w * rb);
  ((ushort4*)(znb + (size_t)i * DD))[lane] = oa;
  ((ushort4*)(znb + (size_t)(i + NB) * DD))[lane] = ob;

  if (lane == 0) sred[wave] = sab * ra * rb;  // exact fp32 pos (row i)
  __syncthreads();
  if (threadIdx.x == 0)
    ppos[blockIdx.x] = sred[0] + sred[1] + sred[2] + sred[3];
}

// ---------------- kernel B: gsum + persistent 2-tile macro + fused tail ---
__global__ __launch_bounds__(512, 4) void den_kernel(const int* __restrict__ sf,
                                                     float* __restrict__ wsf,
                                                     const unsigned short* __restrict__ znb,
                                                     float* __restrict__ vsum_part,
                                                     int* __restrict__ cnt_part,
                                                     const float* __restrict__ ppos,
                                                     float* __restrict__ out,
                                                     int* __restrict__ done_cnt) {
  __shared__ __align__(16) unsigned short As[3][4096];  // 24 KB
  __shared__ __align__(16) unsigned short Bs[3][8192];  // 48 KB
  __shared__ __align__(16) float Escr[1024];            // 4 KB epilogue/tail scratch
  __shared__ int ilast;

  float* den = wsf;
  const int tid = threadIdx.x;
  const int lane = tid & 63, wave = tid >> 6;  // wave 0..7
  const unsigned t_raw = blockIdx.y * 68u + blockIdx.x;
  const unsigned t_lin = (t_raw & 7u) * 68u + (t_raw >> 3);  // bijective XCD swizzle

  if (t_lin < GSUM_BLOCKS) {
    // ---- gsum: 256 rows over 8 waves (32 rows each), LDS reduce ----------
    const int b = (int)t_lin;
    const int r0 = b * 256;
    float acc[4][4];
#pragma unroll
    for (int q = 0; q < 4; ++q)
#pragma unroll
      for (int e = 0; e < 4; ++e) acc[q][e] = 0.f;
    int cnt[4] = {0, 0, 0, 0};
    const int rw = r0 + wave * 32;
    for (int k = 0; k < 32; ++k) {
      int row = rw + k;
      int g = sf[row];
      ushort4 v = ((const ushort4*)(znb + (size_t)row * DD))[lane];
      float f0 = bf2f(v.x), f1 = bf2f(v.y), f2 = bf2f(v.z), f3 = bf2f(v.w);
#pragma unroll
      for (int q = 0; q < 4; ++q) {
        bool sel = (g == q);
        acc[q][0] += sel ? f0 : 0.f;
        acc[q][1] += sel ? f1 : 0.f;
        acc[q][2] += sel ? f2 : 0.f;
        acc[q][3] += sel ? f3 : 0.f;
        cnt[q] += sel ? 1 : 0;
      }
    }
    float4* lsd = (float4*)&Bs[0][0];  // 32 KB
    int* lcnt = (int*)&As[0][0];
#pragma unroll
    for (int q = 0; q < 4; ++q) {
      float4 t;
      t.x = acc[q][0]; t.y = acc[q][1]; t.z = acc[q][2]; t.w = acc[q][3];
      lsd[(wave * 4 + q) * 64 + lane] = t;
    }
    if (lane == 0) {
#pragma unroll
      for (int q = 0; q < 4; ++q) lcnt[wave * 4 + q] = cnt[q];
    }
    __syncthreads();
    if (tid < 256) {
      int g = tid >> 6, l = tid & 63;
      float4 s = {0.f, 0.f, 0.f, 0.f};
#pragma unroll
      for (int w = 0; w < 8; ++w) {
        float4 sv = lsd[(w * 4 + g) * 64 + l];
        s.x += sv.x; s.y += sv.y; s.z += sv.z; s.w += sv.w;
      }
      ((float4*)(vsum_part + (size_t)(b * 4 + g) * 256))[l] = s;
      if (tid < 4) {
        int ci = 0;
#pragma unroll
        for (int w = 0; w < 8; ++w) ci += lcnt[w * 4 + tid];
        cnt_part[b * 4 + tid] = ci;
      }
    }
  } else {
    // ---- persistent macro block: two consecutive 128x256 tiles -----------
    const unsigned idx = t_lin - GSUM_BLOCKS;  // 0..527
    unsigned tr0, c0, tr1, c1;
    {
      unsigned t = 2u * idx, tr = 0;
      while (t >= 32u - (tr >> 1)) { t -= 32u - (tr >> 1); ++tr; }
      tr0 = tr; c0 = (tr >> 1) + t;
      t = 2u * idx + 1u; tr = 0;
      while (t >= 32u - (tr >> 1)) { t -= 32u - (tr >> 1); ++tr; }
      tr1 = tr; c1 = (tr >> 1) + t;
    }

    const int u = lane >> 3;
    const int cp = (lane & 7) ^ u;
    const int ri = 2 * u + (cp >> 2);
    const int kelem = (cp & 3) * 8;
    const int slot = ((((lane & 1) << 2) | (lane >> 4)) ^ ((lane >> 1) & 7));
    const int fragoff = ((lane & 15) >> 1) * 128 + slot * 16;
    const int wrow = wave & 1;   // 64-row half
    const int wcol = wave >> 1;  // 64-col quarter (0..3)

    f32x4 zero = {0.f, 0.f, 0.f, 0.f};
    f32x4 acc[4][4];
#pragma unroll
    for (int i = 0; i < 4; ++i)
#pragma unroll
      for (int j = 0; j < 4; ++j) acc[i][j] = zero;

    // per-phase staging base pointers
    const unsigned short* gA_p0 = znb + ((size_t)tr0 * 128 + wave * 16 + ri) * DD + kelem;
    const unsigned short* gB0_p0 = znb + ((size_t)c0 * 256 + (2 * wave) * 16 + ri) * DD + kelem;
    const unsigned short* gB1_p0 = gB0_p0 + 16 * DD;
    const unsigned short* gA_p1 = znb + ((size_t)tr1 * 128 + wave * 16 + ri) * DD + kelem;
    const unsigned short* gB0_p1 = znb + ((size_t)c1 * 256 + (2 * wave) * 16 + ri) * DD + kelem;
    const unsigned short* gB1_p1 = gB0_p1 + 16 * DD;

    auto stage = [&](int s) {  // s compile-time via unroll: phase s>>3, kt s&7, buf s%3
      const int buf = s % 3, kt = s & 7;
      const unsigned short* gA = (s < 8) ? gA_p0 : gA_p1;
      const unsigned short* gB0 = (s < 8) ? gB0_p0 : gB0_p1;
      const unsigned short* gB1 = (s < 8) ? gB1_p0 : gB1_p1;
      __builtin_amdgcn_global_load_lds((gvoid_t*)(gA + kt * 32), (lvoid_t*)&As[buf][wave * 512], 16, 0, 0);
      __builtin_amdgcn_global_load_lds((gvoid_t*)(gB0 + kt * 32), (lvoid_t*)&Bs[buf][(2 * wave) * 512], 16, 0, 0);
      __builtin_amdgcn_global_load_lds((gvoid_t*)(gB1 + kt * 32), (lvoid_t*)&Bs[buf][(2 * wave + 1) * 512], 16, 0, 0);
    };

    auto epilogue = [&](unsigned tr, unsigned c) {
      const size_t rowbase = (size_t)tr * 128;
      const size_t colbase = (size_t)c * 256;
      const int tch = (int)(2 * c) + (wcol >> 1);     // this wave's 128-col half
      const float fr = (tch >= (int)tr) ? 1.f : 0.f;
      const float fc = (tch > (int)tr) ? 1.f : 0.f;
      float rsum[4][4], csum[4];
#pragma unroll
      for (int mi = 0; mi < 4; ++mi)
#pragma unroll
        for (int r = 0; r < 4; ++r) rsum[mi][r] = 0.f;
#pragma unroll
      for (int ni = 0; ni < 4; ++ni) csum[ni] = 0.f;
#pragma unroll
      for (int mi = 0; mi < 4; ++mi)
#pragma unroll
        for (int ni = 0; ni < 4; ++ni)
#pragma unroll
          for (int r = 0; r < 4; ++r) {
            float e = __expf(2.0f * acc[mi][ni][r]);
            rsum[mi][r] += e;
            csum[ni] += e;
          }
#pragma unroll
      for (int m = 1; m < 16; m <<= 1)
#pragma unroll
        for (int mi = 0; mi < 4; ++mi)
#pragma unroll
          for (int r = 0; r < 4; ++r) rsum[mi][r] += __shfl_xor(rsum[mi][r], m);
#pragma unroll
      for (int m = 16; m < 64; m <<= 1)
#pragma unroll
        for (int ni = 0; ni < 4; ++ni) csum[ni] += __shfl_xor(csum[ni], m);

      float* Lr = &Escr[0];    // [4][128] by wcol
      float* Lc = &Escr[512];  // [2][256] by wrow
      if ((lane & 15) == 0) {
        int h = lane >> 4;
#pragma unroll
        for (int mi = 0; mi < 4; ++mi)
#pragma unroll
          for (int r = 0; r < 4; ++r)
            Lr[wcol * 128 + wrow * 64 + mi * 16 + h * 4 + r] = rsum[mi][r] * fr;
      }
      if (lane < 16) {
#pragma unroll
        for (int ni = 0; ni < 4; ++ni)
          Lc[wrow * 256 + wcol * 64 + ni * 16 + lane] = csum[ni] * fc;
      }
      // raw barrier: LDS-only wait, keeps cross-tile prefetch in flight
      asm volatile("s_waitcnt lgkmcnt(0)" ::: "memory");
      __builtin_amdgcn_s_barrier();
      asm volatile("" ::: "memory");
      if (tid < 256) {
        float v = Lc[tid] + Lc[256 + tid];
        if (v != 0.f) unsafeAtomicAdd(&den[colbase + tid], v);
      } else if (tid < 384) {
        int r = tid - 256;
        unsafeAtomicAdd(&den[rowbase + r], Lr[r] + Lr[128 + r] + Lr[256 + r] + Lr[384 + r]);
      }
#pragma unroll
      for (int i = 0; i < 4; ++i)
#pragma unroll
        for (int j = 0; j < 4; ++j) acc[i][j] = zero;
    };

    // 16-step unified counted-vmcnt pipeline (3 bufs, dist 2)
    stage(0);
    stage(1);
#pragma unroll
    for (int s = 0; s < 16; ++s) {
      const int buf = s % 3;
      if (s < 15) asm volatile("s_waitcnt vmcnt(4)" ::: "memory");
      else        asm volatile("s_waitcnt vmcnt(0)" ::: "memory");
      __builtin_amdgcn_s_barrier();
      asm volatile("" ::: "memory");  // keep stage() below the barrier
      if (s < 14) stage(s + 2);
      short8 af[4], bfr[4];
#pragma unroll
      for (int mi = 0; mi < 4; ++mi)
        af[mi] = *(const short8*)((const char*)&As[0][0] + buf * 8192 + (wrow * 4 + mi) * 1024 + fragoff);
#pragma unroll
      for (int ni = 0; ni < 4; ++ni)
        bfr[ni] = *(const short8*)((const char*)&Bs[0][0] + buf * 16384 + (wcol * 4 + ni) * 1024 + fragoff);
#pragma unroll
      for (int mi = 0; mi < 4; ++mi)
#pragma unroll
        for (int ni = 0; ni < 4; ++ni)
          acc[mi][ni] = __builtin_amdgcn_mfma_f32_16x16x32_bf16(af[mi], bfr[ni], acc[mi][ni], 0, 0, 0);
      if (s == 7) epilogue(tr0, c0);  // tile1's stages 8,9 already in flight
    }
    epilogue(tr1, c1);
  }

  // ---------------- completion + fused tail --------------------------------
  __syncthreads();  // drains each wave's own atomics/stores (vmcnt 0) + sync
  if (tid == 0) {
    if (t_lin < GSUM_BLOCKS) __threadfence();  // flush plain vsum/cnt stores (16 blocks only)
    int prev = __hip_atomic_fetch_add(done_cnt, 1, __ATOMIC_RELAXED, __HIP_MEMORY_SCOPE_AGENT);
    ilast = (prev == (int)NPART - 1) ? 1 : 0;
  }
  __syncthreads();
  if (ilast == 0) return;

  {  // last block: tail on 512 threads, agent-scope loads (bypass caches)
    float* sred = &Escr[0];
    const float e2 = __expf(2.0f);
    float ls = 0.f;
#pragma unroll
    for (int k = 0; k < 16; ++k) {
      float d = __hip_atomic_load(&wsf[k * 512 + tid], __ATOMIC_RELAXED, __HIP_MEMORY_SCOPE_AGENT);
      ls += __logf(d - e2);
    }
#pragma unroll
    for (int m = 32; m >= 1; m >>= 1) ls += __shfl_xor(ls, m);
    if (lane == 0) sred[wave] = ls;

    float pp = ppos[tid] + ppos[512 + tid];
#pragma unroll
    for (int m = 32; m >= 1; m >>= 1) pp += __shfl_xor(pp, m);
    if (lane == 0) sred[8 + wave] = pp;

    {  // group col-sums: g = tid>>7 (wave-uniform), cols col2 and col2+128
      int g = tid >> 7, col2 = tid & 127;
      float v1 = 0.f, v2 = 0.f;
#pragma unroll
      for (int b = 0; b < 16; ++b) {
        v1 += __hip_atomic_load(&vsum_part[(size_t)(b * 4 + g) * 256 + col2],
                                __ATOMIC_RELAXED, __HIP_MEMORY_SCOPE_AGENT);
        v2 += __hip_atomic_load(&vsum_part[(size_t)(b * 4 + g) * 256 + col2 + 128],
                                __ATOMIC_RELAXED, __HIP_MEMORY_SCOPE_AGENT);
      }
      float gp = v1 * v1 + v2 * v2;
#pragma unroll
      for (int m = 32; m >= 1; m >>= 1) gp += __shfl_xor(gp, m);
      if (lane == 0) sred[16 + wave] = gp;  // wave w -> group w>>1
    }
    __syncthreads();
    if (tid == 0) {
      float lsum = 0.f, psum = 0.f;
#pragma unroll
      for (int w = 0; w < 8; ++w) { lsum += sred[w]; psum += sred[8 + w]; }
      float contrastive = (lsum - 4.0f * psum) / (float)TWOB;
      float fsum = 0.f;
      int uniq = 0;
#pragma unroll
      for (int q = 0; q < 4; ++q) {
        int ci = 0;
#pragma unroll
        for (int b = 0; b < 16; ++b)
          ci += __hip_atomic_load(&cnt_part[b * 4 + q], __ATOMIC_RELAXED, __HIP_MEMORY_SCOPE_AGENT);
        float gsq = sred[16 + 2 * q] + sred[17 + 2 * q];
        float cf = (float)ci;
        if (ci > 0) uniq++;
        if (ci > 1) fsum += gsq / (cf * (cf - 1.0f));
      }
      out[0] = contrastive + 0.1f * (fsum / (uniq > 0 ? (float)uniq : 1.0f));
    }
  }
}

extern "C" void kernel_launch(void* const* d_in, const int* in_sizes, int n_in,
                              void* d_out, int out_size, void* d_ws, size_t ws_size,
                              hipStream_t stream) {
  const float* zi = (const float*)d_in[0];
  const float* zj = (const float*)d_in[1];
  const int* sf = (const int*)d_in[2];
  float* out = (float*)d_out;
  char* ws = (char*)d_ws;
  float* wsf = (float*)ws;                              // den
  int* done_cnt = (int*)(ws + 32768);
  unsigned short* znb = (unsigned short*)(ws + 65536);  // 8192x256 bf16 (4MB)
  float* vsum_part = (float*)(ws + 4259840);            // 16x4x256 f32
  int* cnt_part = (int*)(ws + 4276224);                 // 16x4 int
  float* ppos = (float*)(ws + 4276480);                 // 1024 f32

  hipLaunchKernelGGL(norm_kernel, dim3(1024), dim3(256), 0, stream, zi, zj, wsf, ppos, znb);
  hipLaunchKernelGGL(den_kernel, dim3(68, 8), dim3(512), 0, stream,
                     sf, wsf, znb, vsum_part, cnt_part, ppos, out, done_cnt);
}

// Round 8
// 101.414 us; speedup vs baseline: 1.0505x; 1.0505x over previous
//
#include <hip/hip_runtime.h>
#include <hip/hip_bf16.h>

typedef __attribute__((ext_vector_type(8))) short short8;
typedef __attribute__((ext_vector_type(4))) float f32x4;
typedef __attribute__((address_space(1))) const void gvoid_t;
typedef __attribute__((address_space(3))) void lvoid_t;

#define NB 4096   // B
#define DD 256    // D
#define TWOB 8192
#define NMACRO 1056u   // sum_{tr} (32 - tr/2) macro 128x256 tiles
#define GSUM_BLOCKS 16
#define NPART 1072u    // gsum + macro blocks (8 x 134 exactly)

__device__ __forceinline__ unsigned short f2bf(float f) {
  unsigned int u = __float_as_uint(f);
  u += 0x7fffu + ((u >> 16) & 1u);
  return (unsigned short)(u >> 16);
}
__device__ __forceinline__ float bf2f(unsigned short s) {
  return __uint_as_float(((unsigned int)s) << 16);
}

// ws layout (bytes):
//   [0, 32768)          den[8192] f32 (zeroed by norm blocks 0..31)
//   [32768, 32772)      done counter (zeroed by norm block 32)
//   [65536, 4259840)    znb 8192x256 bf16
//   [4259840, 4276224)  vsum_part[16][4][256] f32
//   [4276224, 4276480)  cnt_part[16][4] int
//   [4276480, 4280576)  ppos[1024] f32
//
// R25 = R22 (96.65us: one 128x256 tile/block, 3-buf dist-2 counted-vmcnt
// pipeline, 8 waves x 64x64, 1072=8x134 XCD swizzle) + the R24-validated
// lean fused-tail protocol appended AFTER the unchanged tile code.
// R24 post-mortem: regression came from the persistent 2-tile restructure
// (twice-called epilogue lambda inside a 16-step unrolled loop -> live-set
// blew the (512,4) 128-reg cap: VGPR 64, WRITE_SIZE 13.5MB spill, den
// 47.9us). The fusion protocol itself was clean (absmax 0, one fence).
// Here the K-loop is byte-identical to R22; tail code runs where macro
// state is dead (R18 precedent: fusion kept VGPR at 116).

// ---------------- kernel A: zero den+done; normalize -> znb; ppos ---------
__global__ __launch_bounds__(256) void norm_kernel(const float* __restrict__ zi,
                                                   const float* __restrict__ zj,
                                                   float* __restrict__ wsf,
                                                   float* __restrict__ ppos,
                                                   unsigned short* __restrict__ znb) {
  __shared__ float sred[4];
  if (blockIdx.x < 32) wsf[blockIdx.x * 256 + threadIdx.x] = 0.f;
  if (blockIdx.x == 32 && threadIdx.x == 0) ((int*)(wsf + 8192))[0] = 0;
  const int lane = threadIdx.x & 63, wave = threadIdx.x >> 6;
  const int i = blockIdx.x * 4 + wave;

  float4 a = ((const float4*)(zi + (size_t)i * DD))[lane];
  float4 b = ((const float4*)(zj + (size_t)i * DD))[lane];
  float sa = a.x * a.x + a.y * a.y + a.z * a.z + a.w * a.w;
  float sb = b.x * b.x + b.y * b.y + b.z * b.z + b.w * b.w;
  float sab = a.x * b.x + a.y * b.y + a.z * b.z + a.w * b.w;
#pragma unroll
  for (int m = 32; m >= 1; m >>= 1) {
    sa += __shfl_xor(sa, m);
    sb += __shfl_xor(sb, m);
    sab += __shfl_xor(sab, m);
  }
  float ra = 1.0f / fmaxf(sqrtf(sa), 1e-8f);
  float rb = 1.0f / fmaxf(sqrtf(sb), 1e-8f);
  ushort4 oa, ob;
  oa.x = f2bf(a.x * ra); oa.y = f2bf(a.y * ra); oa.z = f2bf(a.z * ra); oa.w = f2bf(a.w * ra);
  ob.x = f2bf(b.x * rb); ob.y = f2bf(b.y * rb); ob.z = f2bf(b.z * rb); ob.w = f2bf(b.w * rb);
  ((ushort4*)(znb + (size_t)i * DD))[lane] = oa;
  ((ushort4*)(znb + (size_t)(i + NB) * DD))[lane] = ob;

  if (lane == 0) sred[wave] = sab * ra * rb;  // exact fp32 pos (row i)
  __syncthreads();
  if (threadIdx.x == 0)
    ppos[blockIdx.x] = sred[0] + sred[1] + sred[2] + sred[3];
}

// ---------------- kernel B: gsum + macro tiles (R22) + fused tail ---------
__global__ __launch_bounds__(512, 4) void den_kernel(const int* __restrict__ sf,
                                                     float* __restrict__ wsf,
                                                     const unsigned short* __restrict__ znb,
                                                     float* __restrict__ vsum_part,
                                                     int* __restrict__ cnt_part,
                                                     const float* __restrict__ ppos,
                                                     float* __restrict__ out,
                                                     int* __restrict__ done_cnt) {
  __shared__ __align__(16) unsigned short As[3][4096];  // 24 KB (A: 128 rows, 3 bufs)
  __shared__ __align__(16) unsigned short Bs[3][8192];  // 48 KB (B: 256 cols, 3 bufs)
  __shared__ int ilast;

  float* den = wsf;

  const int tid = threadIdx.x;
  const int lane = tid & 63, wave = tid >> 6;  // wave 0..7
  const unsigned t_raw = blockIdx.y * 64u + blockIdx.x;
  if (t_raw >= NPART) return;  // spares (not counted)
  // bijective XCD swizzle: 1072 = 8 x 134
  const unsigned t_lin = (t_raw & 7u) * 134u + (t_raw >> 3);

  if (t_lin < GSUM_BLOCKS) {
    // ---- gsum: 256 rows over 8 waves (32 rows each), LDS reduce ----------
    const int b = (int)t_lin;
    const int r0 = b * 256;
    float acc[4][4];
#pragma unroll
    for (int q = 0; q < 4; ++q)
#pragma unroll
      for (int e = 0; e < 4; ++e) acc[q][e] = 0.f;
    int cnt[4] = {0, 0, 0, 0};
    const int rw = r0 + wave * 32;
    for (int k = 0; k < 32; ++k) {
      int row = rw + k;
      int g = sf[row];
      ushort4 v = ((const ushort4*)(znb + (size_t)row * DD))[lane];
      float f0 = bf2f(v.x), f1 = bf2f(v.y), f2 = bf2f(v.z), f3 = bf2f(v.w);
#pragma unroll
      for (int q = 0; q < 4; ++q) {
        bool sel = (g == q);
        acc[q][0] += sel ? f0 : 0.f;
        acc[q][1] += sel ? f1 : 0.f;
        acc[q][2] += sel ? f2 : 0.f;
        acc[q][3] += sel ? f3 : 0.f;
        cnt[q] += sel ? 1 : 0;
      }
    }
    float4* lsd = (float4*)&Bs[0][0];  // 32 x 64 float4 = 32 KB
    int* lcnt = (int*)&As[0][0];       // 32 ints
#pragma unroll
    for (int q = 0; q < 4; ++q) {
      float4 t;
      t.x = acc[q][0]; t.y = acc[q][1]; t.z = acc[q][2]; t.w = acc[q][3];
      lsd[(wave * 4 + q) * 64 + lane] = t;
    }
    if (lane == 0) {
#pragma unroll
      for (int q = 0; q < 4; ++q) lcnt[wave * 4 + q] = cnt[q];
    }
    __syncthreads();
    if (tid < 256) {
      int g = tid >> 6, l = tid & 63;
      float4 s = {0.f, 0.f, 0.f, 0.f};
#pragma unroll
      for (int w = 0; w < 8; ++w) {
        float4 sv = lsd[(w * 4 + g) * 64 + l];
        s.x += sv.x; s.y += sv.y; s.z += sv.z; s.w += sv.w;
      }
      ((float4*)(vsum_part + (size_t)(b * 4 + g) * 256))[l] = s;
      if (tid < 4) {
        int ci = 0;
#pragma unroll
        for (int w = 0; w < 8; ++w) ci += lcnt[w * 4 + tid];
        cnt_part[b * 4 + tid] = ci;
      }
    }
  } else {
    // ---- one 128x256 macro tile, 8 waves x (64x64) -- R22 verbatim -------
    unsigned t = t_lin - GSUM_BLOCKS;
    unsigned tr = 0;
    while (t >= 32u - (tr >> 1)) { t -= 32u - (tr >> 1); ++tr; }
    unsigned c = (tr >> 1) + t;
    const size_t rowbase = (size_t)tr * 128;
    const size_t colbase = (size_t)c * 256;

    const int u = lane >> 3;
    const int cp = (lane & 7) ^ u;
    const int ri = 2 * u + (cp >> 2);
    const int kelem = (cp & 3) * 8;
    const int slot = ((((lane & 1) << 2) | (lane >> 4)) ^ ((lane >> 1) & 7));
    const int fragoff = ((lane & 15) >> 1) * 128 + slot * 16;
    const int wrow = wave & 1;       // 64-row half
    const int wcol = wave >> 1;      // 64-col quarter (0..3)

    const int tch = (int)(2 * c) + (wcol >> 1);     // this wave's 128-col half
    const float fr = (tch >= (int)tr) ? 1.f : 0.f;  // include in row sums
    const float fc = (tch > (int)tr) ? 1.f : 0.f;   // include in col sums

    f32x4 zero = {0.f, 0.f, 0.f, 0.f};
    f32x4 acc[4][4];
#pragma unroll
    for (int i = 0; i < 4; ++i)
#pragma unroll
      for (int j = 0; j < 4; ++j) acc[i][j] = zero;

    const unsigned short* gA = znb + (rowbase + wave * 16 + ri) * DD + kelem;
    const unsigned short* gB0 = znb + (colbase + (2 * wave) * 16 + ri) * DD + kelem;
    const unsigned short* gB1 = gB0 + 16 * DD;

    auto stage = [&](int kt, int buf) {
      __builtin_amdgcn_global_load_lds((gvoid_t*)(gA + kt * 32), (lvoid_t*)&As[buf][wave * 512], 16, 0, 0);
      __builtin_amdgcn_global_load_lds((gvoid_t*)(gB0 + kt * 32), (lvoid_t*)&Bs[buf][(2 * wave) * 512], 16, 0, 0);
      __builtin_amdgcn_global_load_lds((gvoid_t*)(gB1 + kt * 32), (lvoid_t*)&Bs[buf][(2 * wave + 1) * 512], 16, 0, 0);
    };

    stage(0, 0);
    stage(1, 1);
#pragma unroll
    for (int kt = 0; kt < 8; ++kt) {
      const int buf = kt % 3;
      if (kt < 7) asm volatile("s_waitcnt vmcnt(3)" ::: "memory");
      else        asm volatile("s_waitcnt vmcnt(0)" ::: "memory");
      __builtin_amdgcn_s_barrier();
      asm volatile("" ::: "memory");  // keep stage() below the barrier
      if (kt < 6) stage(kt + 2, (kt + 2) % 3);
      short8 af[4], bfr[4];
#pragma unroll
      for (int mi = 0; mi < 4; ++mi)
        af[mi] = *(const short8*)((const char*)&As[0][0] + buf * 8192 + (wrow * 4 + mi) * 1024 + fragoff);
#pragma unroll
      for (int ni = 0; ni < 4; ++ni)
        bfr[ni] = *(const short8*)((const char*)&Bs[0][0] + buf * 16384 + (wcol * 4 + ni) * 1024 + fragoff);
#pragma unroll
      for (int mi = 0; mi < 4; ++mi)
#pragma unroll
        for (int ni = 0; ni < 4; ++ni)
          acc[mi][ni] = __builtin_amdgcn_mfma_f32_16x16x32_bf16(af[mi], bfr[ni], acc[mi][ni], 0, 0, 0);
    }

    // epilogue (R22 verbatim): e = exp(2S); row/col sums; LDS combine; atomics
    float rsum[4][4];
    float csum[4];
#pragma unroll
    for (int mi = 0; mi < 4; ++mi)
#pragma unroll
      for (int r = 0; r < 4; ++r) rsum[mi][r] = 0.f;
#pragma unroll
    for (int ni = 0; ni < 4; ++ni) csum[ni] = 0.f;
#pragma unroll
    for (int mi = 0; mi < 4; ++mi)
#pragma unroll
      for (int ni = 0; ni < 4; ++ni)
#pragma unroll
        for (int r = 0; r < 4; ++r) {
          float e = __expf(2.0f * acc[mi][ni][r]);
          rsum[mi][r] += e;
          csum[ni] += e;
        }
#pragma unroll
    for (int m = 1; m < 16; m <<= 1)
#pragma unroll
      for (int mi = 0; mi < 4; ++mi)
#pragma unroll
        for (int r = 0; r < 4; ++r) rsum[mi][r] += __shfl_xor(rsum[mi][r], m);
#pragma unroll
    for (int m = 16; m < 64; m <<= 1)
#pragma unroll
      for (int ni = 0; ni < 4; ++ni) csum[ni] += __shfl_xor(csum[ni], m);

    float* Lr = (float*)&As[0][0];  // [4][128] indexed by wcol (2 KB)
    float* Lc = Lr + 512;           // [2][256] indexed by wrow (2 KB)
    if ((lane & 15) == 0) {
      int h = lane >> 4;
#pragma unroll
      for (int mi = 0; mi < 4; ++mi)
#pragma unroll
        for (int r = 0; r < 4; ++r)
          Lr[wcol * 128 + wrow * 64 + mi * 16 + h * 4 + r] = rsum[mi][r] * fr;
    }
    if (lane < 16) {
#pragma unroll
      for (int ni = 0; ni < 4; ++ni)
        Lc[wrow * 256 + wcol * 64 + ni * 16 + lane] = csum[ni] * fc;
    }
    __syncthreads();
    if (tid < 256) {
      float v = Lc[tid] + Lc[256 + tid];
      if (v != 0.f) unsafeAtomicAdd(&den[colbase + tid], v);
    } else if (tid < 384) {
      int r = tid - 256;
      unsafeAtomicAdd(&den[rowbase + r], Lr[r] + Lr[128 + r] + Lr[256 + r] + Lr[384 + r]);
    }
  }

  // ---------------- completion + fused tail (R24-validated protocol) ------
  __syncthreads();  // drains each wave's own atomics/stores + block sync
  if (tid == 0) {
    if (t_lin < GSUM_BLOCKS) __threadfence();  // flush plain vsum/cnt (16 blocks)
    int prev = __hip_atomic_fetch_add(done_cnt, 1, __ATOMIC_RELAXED, __HIP_MEMORY_SCOPE_AGENT);
    ilast = (prev == (int)NPART - 1) ? 1 : 0;
  }
  __syncthreads();
  if (ilast == 0) return;

  {  // last block: tail on 512 threads, agent-scope loads
    float* sred = (float*)&As[0][0];
    const float e2 = __expf(2.0f);
    float ls = 0.f;
#pragma unroll
    for (int k = 0; k < 16; ++k) {
      float d = __hip_atomic_load(&wsf[k * 512 + tid], __ATOMIC_RELAXED, __HIP_MEMORY_SCOPE_AGENT);
      ls += __logf(d - e2);
    }
#pragma unroll
    for (int m = 32; m >= 1; m >>= 1) ls += __shfl_xor(ls, m);
    if (lane == 0) sred[wave] = ls;

    float pp = ppos[tid] + ppos[512 + tid];
#pragma unroll
    for (int m = 32; m >= 1; m >>= 1) pp += __shfl_xor(pp, m);
    if (lane == 0) sred[8 + wave] = pp;

    {  // group col-sums: g = tid>>7 (wave-uniform), cols col2 and col2+128
      int g = tid >> 7, col2 = tid & 127;
      float v1 = 0.f, v2 = 0.f;
#pragma unroll
      for (int b = 0; b < 16; ++b) {
        v1 += __hip_atomic_load(&vsum_part[(size_t)(b * 4 + g) * 256 + col2],
                                __ATOMIC_RELAXED, __HIP_MEMORY_SCOPE_AGENT);
        v2 += __hip_atomic_load(&vsum_part[(size_t)(b * 4 + g) * 256 + col2 + 128],
                                __ATOMIC_RELAXED, __HIP_MEMORY_SCOPE_AGENT);
      }
      float gp = v1 * v1 + v2 * v2;
#pragma unroll
      for (int m = 32; m >= 1; m >>= 1) gp += __shfl_xor(gp, m);
      if (lane == 0) sred[16 + wave] = gp;  // wave w -> group w>>1
    }
    __syncthreads();
    if (tid == 0) {
      float lsum = 0.f, psum = 0.f;
#pragma unroll
      for (int w = 0; w < 8; ++w) { lsum += sred[w]; psum += sred[8 + w]; }
      float contrastive = (lsum - 4.0f * psum) / (float)TWOB;
      float fsum = 0.f;
      int uniq = 0;
#pragma unroll
      for (int q = 0; q < 4; ++q) {
        int ci = 0;
#pragma unroll
        for (int b = 0; b < 16; ++b)
          ci += __hip_atomic_load(&cnt_part[b * 4 + q], __ATOMIC_RELAXED, __HIP_MEMORY_SCOPE_AGENT);
        float gsq = sred[16 + 2 * q] + sred[17 + 2 * q];
        float cf = (float)ci;
        if (ci > 0) uniq++;
        if (ci > 1) fsum += gsq / (cf * (cf - 1.0f));
      }
      out[0] = contrastive + 0.1f * (fsum / (uniq > 0 ? (float)uniq : 1.0f));
    }
  }
}

extern "C" void kernel_launch(void* const* d_in, const int* in_sizes, int n_in,
                              void* d_out, int out_size, void* d_ws, size_t ws_size,
                              hipStream_t stream) {
  const float* zi = (const float*)d_in[0];
  const float* zj = (const float*)d_in[1];
  const int* sf = (const int*)d_in[2];
  float* out = (float*)d_out;
  char* ws = (char*)d_ws;
  float* wsf = (float*)ws;                              // den
  int* done_cnt = (int*)(ws + 32768);
  unsigned short* znb = (unsigned short*)(ws + 65536);  // 8192x256 bf16 (4MB)
  float* vsum_part = (float*)(ws + 4259840);            // 16x4x256 f32
  int* cnt_part = (int*)(ws + 4276224);                 // 16x4 int
  float* ppos = (float*)(ws + 4276480);                 // 1024 f32

  hipLaunchKernelGGL(norm_kernel, dim3(1024), dim3(256), 0, stream, zi, zj, wsf, ppos, znb);
  hipLaunchKernelGGL(den_kernel, dim3(64, 17), dim3(512), 0, stream,
                     sf, wsf, znb, vsum_part, cnt_part, ppos, out, done_cnt);
}